// Round 13
// baseline (43.926 us; speedup 1.0000x reference)
//
#include <hip/hip_runtime.h>
#include <math.h>

#define DIM     128
#define V_ROWS  20000
#define NPAIRS  65536
#define NFLOAT4 (V_ROWS * DIM / 4)   // 640000

constexpr int K1_BLOCKS  = 128;
constexpr int K1_THREADS = 512;
constexpr int K1_STRIDE  = K1_BLOCKS * K1_THREADS;       // 65536 float4
constexpr int K1_TAIL    = NFLOAT4 - 9 * K1_STRIDE;      // 50176

constexpr int K2_BLOCKS  = 512;      // 512 x 8 waves = 4096 waves x 16 pairs
constexpr int K2_THREADS = 512;

// ws layout: partial[128*128] f, blockpart[512] f, flag[512] u32

// ---------------- K1: per-block column partial sums + flag re-zero ---------
__global__ __launch_bounds__(K1_THREADS) void k1_colsum(
        const float4* __restrict__ emb4,
        float* __restrict__ partial,
        unsigned int* __restrict__ flag) {
    // re-zero k2's arrival flags each call (visible at k2 dispatch boundary)
    if (blockIdx.x == 0) flag[threadIdx.x] = 0u;

    const int tid = blockIdx.x * K1_THREADS + threadIdx.x;
    float4 a0 = make_float4(0.f, 0.f, 0.f, 0.f);
    float4 a1 = a0;
    #pragma unroll
    for (int k = 0; k < 8; k += 2) {              // 8 loads, 2 indep chains
        const float4 v0 = emb4[tid + (k + 0) * K1_STRIDE];
        const float4 v1 = emb4[tid + (k + 1) * K1_STRIDE];
        a0.x += v0.x; a0.y += v0.y; a0.z += v0.z; a0.w += v0.w;
        a1.x += v1.x; a1.y += v1.y; a1.z += v1.z; a1.w += v1.w;
    }
    {   // round 8 + predicated tail round 9
        const float4 v0 = emb4[tid + 8 * K1_STRIDE];
        a0.x += v0.x; a0.y += v0.y; a0.z += v0.z; a0.w += v0.w;
        if (tid < K1_TAIL) {
            const float4 v1 = emb4[tid + 9 * K1_STRIDE];
            a1.x += v1.x; a1.y += v1.y; a1.z += v1.z; a1.w += v1.w;
        }
    }
    float4 a = make_float4(a0.x + a1.x, a0.y + a1.y,
                           a0.z + a1.z, a0.w + a1.w);
    // stride*4 % 128 == 0 -> thread's 4 cols fixed: (tid*4)&127.
    // lane l and l^32 share columns -> fold wave to 32 lanes.
    a.x += __shfl_xor(a.x, 32);
    a.y += __shfl_xor(a.y, 32);
    a.z += __shfl_xor(a.z, 32);
    a.w += __shfl_xor(a.w, 32);

    __shared__ float sm[8][DIM];          // 8 waves per block
    const int wid  = threadIdx.x >> 6;
    const int lane = threadIdx.x & 63;
    const int col  = (threadIdx.x * 4) & 127;
    if (lane < 32) {
        sm[wid][col + 0] = a.x;
        sm[wid][col + 1] = a.y;
        sm[wid][col + 2] = a.z;
        sm[wid][col + 3] = a.w;
    }
    __syncthreads();
    if (threadIdx.x < DIM) {
        float tot = 0.f;
        #pragma unroll
        for (int w = 0; w < 8; ++w) tot += sm[w][threadIdx.x];
        partial[blockIdx.x * DIM + threadIdx.x] = tot;
    }
}

// ---- K2: fold->S_lds, pairs, per-block sum; block 0 polls flags + reduces -
__global__ __launch_bounds__(K2_THREADS) void k2_pairs(
        const float4* __restrict__ emb4,      // rows as 32 x float4
        const int* __restrict__ iv,
        const int* __restrict__ jv,
        const float4* __restrict__ partial4,  // [128][32] float4
        float* __restrict__ blockpart,
        unsigned int* __restrict__ flag,
        float* __restrict__ out) {
    const int lane = threadIdx.x & 63;
    const int wid  = threadIdx.x >> 6;     // 0..7

    __shared__ float4 sm4[16][32];
    __shared__ float  S_lds[DIM];
    __shared__ float  ls[8];

    // ---- fold 128 partial rows -> S_lds (8 f4 loads/thread, 2 chains) -----
    {
        const int f4c = threadIdx.x & 31;     // float4 column 0..31
        const int g   = threadIdx.x >> 5;     // row group 0..15, 8 rows each
        float4 c0 = make_float4(0.f, 0.f, 0.f, 0.f);
        float4 c1 = c0;
        #pragma unroll
        for (int k = 0; k < 8; k += 2) {
            const float4 v0 = partial4[(g + 16 * (k + 0)) * 32 + f4c];
            const float4 v1 = partial4[(g + 16 * (k + 1)) * 32 + f4c];
            c0.x += v0.x; c0.y += v0.y; c0.z += v0.z; c0.w += v0.w;
            c1.x += v1.x; c1.y += v1.y; c1.z += v1.z; c1.w += v1.w;
        }
        float4 s;
        s.x = c0.x + c1.x; s.y = c0.y + c1.y;
        s.z = c0.z + c1.z; s.w = c0.w + c1.w;
        sm4[g][f4c] = s;
        __syncthreads();
        if (threadIdx.x < DIM) {
            const float* smf = reinterpret_cast<const float*>(sm4); // [16][128]
            float tot = 0.f;
            #pragma unroll
            for (int g2 = 0; g2 < 16; ++g2) tot += smf[g2 * DIM + threadIdx.x];
            S_lds[threadIdx.x] = tot;
        }
        __syncthreads();
    }

    // ---------------- pairs: 16 lanes/pair, 16 pairs/wave, ONE round -------
    const int c    = lane & 15;            // 8 cols per lane
    const int grp  = lane >> 4;            // 4 pairs in flight per batch
    const int gw   = blockIdx.x * 8 + wid; // 0..4095
    const int base = gw * 16;              // wave's 16 consecutive pairs

    const float4* S4 = reinterpret_cast<const float4*>(S_lds);
    const float4 s0 = S4[c * 2], s1 = S4[c * 2 + 1];

    // coalesced index load: lanes 0..15 -> iv, lanes 16..31 -> jv
    int idxval = 0;
    if (lane < 16)      idxval = iv[base + lane];
    else if (lane < 32) idxval = jv[base + lane - 16];

    // issue ALL 16 row-pair gathers before any reduction
    float4 A0[4], A1[4], B0[4], B1[4];
    #pragma unroll
    for (int it = 0; it < 4; ++it) {
        const int q = it * 4 + grp;
        const int i = __shfl(idxval, q);
        const int j = __shfl(idxval, 16 + q);
        const float4* ei = emb4 + (size_t)i * 32;
        const float4* ej = emb4 + (size_t)j * 32;
        A0[it] = ei[c * 2]; A1[it] = ei[c * 2 + 1];
        B0[it] = ej[c * 2]; B1[it] = ej[c * 2 + 1];
    }

    float acc = 0.f;
    #pragma unroll
    for (int it = 0; it < 4; ++it) {
        float d = A0[it].x * B0[it].x + A0[it].y * B0[it].y
                + A0[it].z * B0[it].z + A0[it].w * B0[it].w
                + A1[it].x * B1[it].x + A1[it].y * B1[it].y
                + A1[it].z * B1[it].z + A1[it].w * B1[it].w;
        float n = A0[it].x * s0.x + A0[it].y * s0.y
                + A0[it].z * s0.z + A0[it].w * s0.w
                + A1[it].x * s1.x + A1[it].y * s1.y
                + A1[it].z * s1.z + A1[it].w * s1.w;
        #pragma unroll
        for (int off = 8; off > 0; off >>= 1) {
            d += __shfl_xor(d, off);
            n += __shfl_xor(n, off);
        }
        const float cost = -__logf(__expf(d - n) + 1e-8f);
        if (c == 0) acc += cost;           // grp leaders only
    }
    // fold grp leaders (lanes 0,16,32,48) -> lane 0
    acc += __shfl_xor(acc, 16);
    acc += __shfl_xor(acc, 32);

    if (lane == 0) ls[wid] = acc;
    __syncthreads();
    if (threadIdx.x == 0) {
        float s = 0.f;
        #pragma unroll
        for (int w = 0; w < 8; ++w) s += ls[w];
        blockpart[blockIdx.x] = s;
        __threadfence();                   // blockpart visible agent-wide
        __hip_atomic_store(&flag[blockIdx.x], 1u,
                           __ATOMIC_RELEASE, __HIP_MEMORY_SCOPE_AGENT);
    }

    // ---- block 0: poll all 512 flags (1/thread), reduce, write mean -------
    if (blockIdx.x == 0) {
        const int t = threadIdx.x;         // 0..511, one flag each
        while (__hip_atomic_load(&flag[t], __ATOMIC_ACQUIRE,
                                 __HIP_MEMORY_SCOPE_AGENT) == 0u) {
            __builtin_amdgcn_s_sleep(2);
        }
        // agent-scope load: avoid stale local L2 copy of blockpart
        float v;
        {
            const float* bp = &blockpart[t];
            v = __hip_atomic_load(bp, __ATOMIC_RELAXED,
                                  __HIP_MEMORY_SCOPE_AGENT);
        }
        #pragma unroll
        for (int off = 32; off > 0; off >>= 1) v += __shfl_xor(v, off);
        __syncthreads();                   // ls reuse barrier
        if (lane == 0) ls[wid] = v;
        __syncthreads();
        if (t == 0) {
            float tot = 0.f;
            #pragma unroll
            for (int w = 0; w < 8; ++w) tot += ls[w];
            out[0] = tot / (float)NPAIRS;
        }
    }
}

extern "C" void kernel_launch(void* const* d_in, const int* in_sizes, int n_in,
                              void* d_out, int out_size, void* d_ws, size_t ws_size,
                              hipStream_t stream) {
    const float4* emb4 = (const float4*)d_in[0];
    const int*    iv   = (const int*)d_in[1];
    const int*    jv   = (const int*)d_in[2];
    float* out = (float*)d_out;

    float* partial        = (float*)d_ws;                  // 128*128
    float* blockpart      = partial + K1_BLOCKS * DIM;     // 512
    unsigned int* flag    = (unsigned int*)(blockpart + K2_BLOCKS); // 512

    hipLaunchKernelGGL(k1_colsum, dim3(K1_BLOCKS), dim3(K1_THREADS), 0, stream,
                       emb4, partial, flag);
    hipLaunchKernelGGL(k2_pairs, dim3(K2_BLOCKS), dim3(K2_THREADS), 0, stream,
                       emb4, iv, jv, (const float4*)partial, blockpart, flag, out);
}

// Round 14
// 22.598 us; speedup vs baseline: 1.9438x; 1.9438x over previous
//
#include <hip/hip_runtime.h>
#include <math.h>

#define DIM     128
#define V_ROWS  20000
#define NPAIRS  65536
#define NFLOAT4 (V_ROWS * DIM / 4)   // 640000

constexpr int K1_BLOCKS  = 128;
constexpr int K1_THREADS = 512;
constexpr int K1_STRIDE  = K1_BLOCKS * K1_THREADS;       // 65536 float4
constexpr int K1_TAIL    = NFLOAT4 - 9 * K1_STRIDE;      // 50176

constexpr int K2_BLOCKS  = 512;      // 512 x 8 waves = 4096 waves x 16 pairs
constexpr int K2_THREADS = 512;

#define FXS 1048576.0                // 2^20 fixed-point scale

// ws layout: accPack u64 @0, partial[128*128] f @32B

// ---------------- K1: per-block column partial sums + acc re-zero ----------
__global__ __launch_bounds__(K1_THREADS) void k1_colsum(
        const float4* __restrict__ emb4,
        float* __restrict__ partial,
        unsigned long long* __restrict__ accPack) {
    if (blockIdx.x == 0 && threadIdx.x == 0) *accPack = 0ull;  // per-call reset

    const int tid = blockIdx.x * K1_THREADS + threadIdx.x;
    float4 a0 = make_float4(0.f, 0.f, 0.f, 0.f);
    float4 a1 = a0;
    #pragma unroll
    for (int k = 0; k < 8; k += 2) {              // 8 loads, 2 indep chains
        const float4 v0 = emb4[tid + (k + 0) * K1_STRIDE];
        const float4 v1 = emb4[tid + (k + 1) * K1_STRIDE];
        a0.x += v0.x; a0.y += v0.y; a0.z += v0.z; a0.w += v0.w;
        a1.x += v1.x; a1.y += v1.y; a1.z += v1.z; a1.w += v1.w;
    }
    {   // round 8 + predicated tail round 9
        const float4 v0 = emb4[tid + 8 * K1_STRIDE];
        a0.x += v0.x; a0.y += v0.y; a0.z += v0.z; a0.w += v0.w;
        if (tid < K1_TAIL) {
            const float4 v1 = emb4[tid + 9 * K1_STRIDE];
            a1.x += v1.x; a1.y += v1.y; a1.z += v1.z; a1.w += v1.w;
        }
    }
    float4 a = make_float4(a0.x + a1.x, a0.y + a1.y,
                           a0.z + a1.z, a0.w + a1.w);
    // stride*4 % 128 == 0 -> thread's 4 cols fixed: (tid*4)&127.
    // lane l and l^32 share columns -> fold wave to 32 lanes.
    a.x += __shfl_xor(a.x, 32);
    a.y += __shfl_xor(a.y, 32);
    a.z += __shfl_xor(a.z, 32);
    a.w += __shfl_xor(a.w, 32);

    __shared__ float sm[8][DIM];          // 8 waves per block
    const int wid  = threadIdx.x >> 6;
    const int lane = threadIdx.x & 63;
    const int col  = (threadIdx.x * 4) & 127;
    if (lane < 32) {
        sm[wid][col + 0] = a.x;
        sm[wid][col + 1] = a.y;
        sm[wid][col + 2] = a.z;
        sm[wid][col + 3] = a.w;
    }
    __syncthreads();
    if (threadIdx.x < DIM) {
        float tot = 0.f;
        #pragma unroll
        for (int w = 0; w < 8; ++w) tot += sm[w][threadIdx.x];
        partial[blockIdx.x * DIM + threadIdx.x] = tot;
    }
}

// ---- K2: fold->S_lds, pairs; ONE packed atomic per block; last writes out -
__global__ __launch_bounds__(K2_THREADS) void k2_pairs(
        const float4* __restrict__ emb4,      // rows as 32 x float4
        const int* __restrict__ iv,
        const int* __restrict__ jv,
        const float4* __restrict__ partial4,  // [128][32] float4
        unsigned long long* __restrict__ accPack,
        float* __restrict__ out) {
    const int lane = threadIdx.x & 63;
    const int wid  = threadIdx.x >> 6;     // 0..7

    __shared__ float4 sm4[16][32];
    __shared__ float  S_lds[DIM];
    __shared__ float  ls[8];

    // ---- fold 128 partial rows -> S_lds (8 f4 loads/thread, 2 chains) -----
    {
        const int f4c = threadIdx.x & 31;     // float4 column 0..31
        const int g   = threadIdx.x >> 5;     // row group 0..15, 8 rows each
        float4 c0 = make_float4(0.f, 0.f, 0.f, 0.f);
        float4 c1 = c0;
        #pragma unroll
        for (int k = 0; k < 8; k += 2) {
            const float4 v0 = partial4[(g + 16 * (k + 0)) * 32 + f4c];
            const float4 v1 = partial4[(g + 16 * (k + 1)) * 32 + f4c];
            c0.x += v0.x; c0.y += v0.y; c0.z += v0.z; c0.w += v0.w;
            c1.x += v1.x; c1.y += v1.y; c1.z += v1.z; c1.w += v1.w;
        }
        float4 s;
        s.x = c0.x + c1.x; s.y = c0.y + c1.y;
        s.z = c0.z + c1.z; s.w = c0.w + c1.w;
        sm4[g][f4c] = s;
        __syncthreads();
        if (threadIdx.x < DIM) {
            const float* smf = reinterpret_cast<const float*>(sm4); // [16][128]
            float tot = 0.f;
            #pragma unroll
            for (int g2 = 0; g2 < 16; ++g2) tot += smf[g2 * DIM + threadIdx.x];
            S_lds[threadIdx.x] = tot;
        }
        __syncthreads();
    }

    // ---------------- pairs: 16 lanes/pair, 16 pairs/wave, ONE round -------
    const int c    = lane & 15;            // 8 cols per lane
    const int grp  = lane >> 4;            // 4 pairs in flight per batch
    const int gw   = blockIdx.x * 8 + wid; // 0..4095
    const int base = gw * 16;              // wave's 16 consecutive pairs

    const float4* S4 = reinterpret_cast<const float4*>(S_lds);
    const float4 s0 = S4[c * 2], s1 = S4[c * 2 + 1];

    // coalesced index load: lanes 0..15 -> iv, lanes 16..31 -> jv
    int idxval = 0;
    if (lane < 16)      idxval = iv[base + lane];
    else if (lane < 32) idxval = jv[base + lane - 16];

    // issue ALL 16 row-pair gathers before any reduction
    float4 A0[4], A1[4], B0[4], B1[4];
    #pragma unroll
    for (int it = 0; it < 4; ++it) {
        const int q = it * 4 + grp;
        const int i = __shfl(idxval, q);
        const int j = __shfl(idxval, 16 + q);
        const float4* ei = emb4 + (size_t)i * 32;
        const float4* ej = emb4 + (size_t)j * 32;
        A0[it] = ei[c * 2]; A1[it] = ei[c * 2 + 1];
        B0[it] = ej[c * 2]; B1[it] = ej[c * 2 + 1];
    }

    float acc = 0.f;
    #pragma unroll
    for (int it = 0; it < 4; ++it) {
        float d = A0[it].x * B0[it].x + A0[it].y * B0[it].y
                + A0[it].z * B0[it].z + A0[it].w * B0[it].w
                + A1[it].x * B1[it].x + A1[it].y * B1[it].y
                + A1[it].z * B1[it].z + A1[it].w * B1[it].w;
        float n = A0[it].x * s0.x + A0[it].y * s0.y
                + A0[it].z * s0.z + A0[it].w * s0.w
                + A1[it].x * s1.x + A1[it].y * s1.y
                + A1[it].z * s1.z + A1[it].w * s1.w;
        #pragma unroll
        for (int off = 8; off > 0; off >>= 1) {
            d += __shfl_xor(d, off);
            n += __shfl_xor(n, off);
        }
        const float cost = -__logf(__expf(d - n) + 1e-8f);
        if (c == 0) acc += cost;           // grp leaders only
    }
    // fold grp leaders (lanes 0,16,32,48) -> lane 0
    acc += __shfl_xor(acc, 16);
    acc += __shfl_xor(acc, 32);

    if (lane == 0) ls[wid] = acc;
    __syncthreads();
    if (threadIdx.x == 0) {
        const double bsum = (double)(((ls[0] + ls[1]) + (ls[2] + ls[3])) +
                                     ((ls[4] + ls[5]) + (ls[6] + ls[7])));
        const long long q = __double2ll_rn(bsum * FXS);
        // pack: value in bits [10,63] (two's complement), arrival count in [0,9].
        // value adds are multiples of 2^10 -> never touch count bits;
        // counts sum to 512 < 1024 -> never carry into value bits.
        const unsigned long long addend =
            ((unsigned long long)(long long)q << 10) + 1ull;
        const unsigned long long old = atomicAdd(accPack, addend);
        if ((old & 1023ull) == (unsigned long long)(K2_BLOCKS - 1)) {
            // I'm the 512th arrival: old+addend holds every contribution.
            const unsigned long long tot = old + addend;
            const long long sq = ((long long)tot) >> 10;   // drop count bits
            out[0] = (float)((double)sq * (1.0 / FXS) / (double)NPAIRS);
        }
    }
}

extern "C" void kernel_launch(void* const* d_in, const int* in_sizes, int n_in,
                              void* d_out, int out_size, void* d_ws, size_t ws_size,
                              hipStream_t stream) {
    const float4* emb4 = (const float4*)d_in[0];
    const int*    iv   = (const int*)d_in[1];
    const int*    jv   = (const int*)d_in[2];
    float* out = (float*)d_out;

    unsigned long long* accPack = (unsigned long long*)d_ws;
    float* partial = (float*)((char*)d_ws + 32);     // 128*128 floats

    hipLaunchKernelGGL(k1_colsum, dim3(K1_BLOCKS), dim3(K1_THREADS), 0, stream,
                       emb4, partial, accPack);
    hipLaunchKernelGGL(k2_pairs, dim3(K2_BLOCKS), dim3(K2_THREADS), 0, stream,
                       emb4, iv, jv, (const float4*)partial, accPack, out);
}

// Round 15
// 20.381 us; speedup vs baseline: 2.1552x; 1.1088x over previous
//
#include <hip/hip_runtime.h>
#include <math.h>

#define DIM     128
#define V_ROWS  20000
#define NPAIRS  65536
#define NFLOAT4 (V_ROWS * DIM / 4)   // 640000

constexpr int K1_BLOCKS  = 128;
constexpr int K1_THREADS = 512;
constexpr int K1_STRIDE  = K1_BLOCKS * K1_THREADS;       // 65536 float4
constexpr int K1_TAIL    = NFLOAT4 - 9 * K1_STRIDE;      // 50176

constexpr int K2_BLOCKS  = 512;      // 512 x 8 waves = 4096 waves x 16 pairs
constexpr int K2_THREADS = 512;

// ws layout (floats): partial[128*128], blockpart[512]

// ---------------- K1: per-block column partial sums (plain stores) ---------
__global__ __launch_bounds__(K1_THREADS) void k1_colsum(
        const float4* __restrict__ emb4,
        float* __restrict__ partial) {
    const int tid = blockIdx.x * K1_THREADS + threadIdx.x;
    float4 a0 = make_float4(0.f, 0.f, 0.f, 0.f);
    float4 a1 = a0;
    #pragma unroll
    for (int k = 0; k < 8; k += 2) {              // 8 loads, 2 indep chains
        const float4 v0 = emb4[tid + (k + 0) * K1_STRIDE];
        const float4 v1 = emb4[tid + (k + 1) * K1_STRIDE];
        a0.x += v0.x; a0.y += v0.y; a0.z += v0.z; a0.w += v0.w;
        a1.x += v1.x; a1.y += v1.y; a1.z += v1.z; a1.w += v1.w;
    }
    {   // round 8 + predicated tail round 9
        const float4 v0 = emb4[tid + 8 * K1_STRIDE];
        a0.x += v0.x; a0.y += v0.y; a0.z += v0.z; a0.w += v0.w;
        if (tid < K1_TAIL) {
            const float4 v1 = emb4[tid + 9 * K1_STRIDE];
            a1.x += v1.x; a1.y += v1.y; a1.z += v1.z; a1.w += v1.w;
        }
    }
    float4 a = make_float4(a0.x + a1.x, a0.y + a1.y,
                           a0.z + a1.z, a0.w + a1.w);
    // stride*4 % 128 == 0 -> thread's 4 cols fixed: (tid*4)&127.
    // lane l and l^32 share columns -> fold wave to 32 lanes.
    a.x += __shfl_xor(a.x, 32);
    a.y += __shfl_xor(a.y, 32);
    a.z += __shfl_xor(a.z, 32);
    a.w += __shfl_xor(a.w, 32);

    __shared__ float sm[8][DIM];          // 8 waves per block
    const int wid  = threadIdx.x >> 6;
    const int lane = threadIdx.x & 63;
    const int col  = (threadIdx.x * 4) & 127;
    if (lane < 32) {
        sm[wid][col + 0] = a.x;
        sm[wid][col + 1] = a.y;
        sm[wid][col + 2] = a.z;
        sm[wid][col + 3] = a.w;
    }
    __syncthreads();
    if (threadIdx.x < DIM) {
        float tot = 0.f;
        #pragma unroll
        for (int w = 0; w < 8; ++w) tot += sm[w][threadIdx.x];
        partial[blockIdx.x * DIM + threadIdx.x] = tot;
    }
}

// ------- K2: fold -> S_lds, pairs with FUSED m = e_i.(e_j - S) dot ---------
__global__ __launch_bounds__(K2_THREADS) void k2_pairs(
        const float4* __restrict__ emb4,      // rows as 32 x float4
        const int* __restrict__ iv,
        const int* __restrict__ jv,
        const float4* __restrict__ partial4,  // [128][32] float4
        float* __restrict__ blockpart) {
    const int lane = threadIdx.x & 63;
    const int wid  = threadIdx.x >> 6;     // 0..7

    __shared__ float4 sm4[16][32];
    __shared__ float  S_lds[DIM];
    __shared__ float  ls[8];

    // ---- fold 128 partial rows -> S_lds (8 f4 loads/thread, 2 chains) -----
    {
        const int f4c = threadIdx.x & 31;     // float4 column 0..31
        const int g   = threadIdx.x >> 5;     // row group 0..15, 8 rows each
        float4 c0 = make_float4(0.f, 0.f, 0.f, 0.f);
        float4 c1 = c0;
        #pragma unroll
        for (int k = 0; k < 8; k += 2) {
            const float4 v0 = partial4[(g + 16 * (k + 0)) * 32 + f4c];
            const float4 v1 = partial4[(g + 16 * (k + 1)) * 32 + f4c];
            c0.x += v0.x; c0.y += v0.y; c0.z += v0.z; c0.w += v0.w;
            c1.x += v1.x; c1.y += v1.y; c1.z += v1.z; c1.w += v1.w;
        }
        float4 s;
        s.x = c0.x + c1.x; s.y = c0.y + c1.y;
        s.z = c0.z + c1.z; s.w = c0.w + c1.w;
        sm4[g][f4c] = s;
        __syncthreads();
        if (threadIdx.x < DIM) {
            const float* smf = reinterpret_cast<const float*>(sm4); // [16][128]
            float tot = 0.f;
            #pragma unroll
            for (int g2 = 0; g2 < 16; ++g2) tot += smf[g2 * DIM + threadIdx.x];
            S_lds[threadIdx.x] = tot;
        }
        __syncthreads();
    }

    // ---------------- pairs: 16 lanes/pair, 16 pairs/wave, ONE round -------
    const int c    = lane & 15;            // 8 cols per lane
    const int grp  = lane >> 4;            // 4 pairs in flight per batch
    const int gw   = blockIdx.x * 8 + wid; // 0..4095
    const int base = gw * 16;              // wave's 16 consecutive pairs

    const float4* S4 = reinterpret_cast<const float4*>(S_lds);
    const float4 s0 = S4[c * 2], s1 = S4[c * 2 + 1];

    // coalesced index load: lanes 0..15 -> iv, lanes 16..31 -> jv
    int idxval = 0;
    if (lane < 16)      idxval = iv[base + lane];
    else if (lane < 32) idxval = jv[base + lane - 16];

    // issue ALL 16 row-pair gathers before any reduction
    float4 A0[4], A1[4], B0[4], B1[4];
    #pragma unroll
    for (int it = 0; it < 4; ++it) {
        const int q = it * 4 + grp;
        const int i = __shfl(idxval, q);
        const int j = __shfl(idxval, 16 + q);
        const float4* ei = emb4 + (size_t)i * 32;
        const float4* ej = emb4 + (size_t)j * 32;
        A0[it] = ei[c * 2]; A1[it] = ei[c * 2 + 1];
        B0[it] = ej[c * 2]; B1[it] = ej[c * 2 + 1];
    }

    float acc = 0.f;
    #pragma unroll
    for (int it = 0; it < 4; ++it) {
        // fused dot: m = e_i . (e_j - S)  ==  d - n   (exact)
        float m = A0[it].x * (B0[it].x - s0.x) + A0[it].y * (B0[it].y - s0.y)
                + A0[it].z * (B0[it].z - s0.z) + A0[it].w * (B0[it].w - s0.w)
                + A1[it].x * (B1[it].x - s1.x) + A1[it].y * (B1[it].y - s1.y)
                + A1[it].z * (B1[it].z - s1.z) + A1[it].w * (B1[it].w - s1.w);
        // ONE 4-level reduce chain (was two: d and n separately)
        #pragma unroll
        for (int off = 8; off > 0; off >>= 1) m += __shfl_xor(m, off);
        const float cost = -__logf(__expf(m) + 1e-8f);
        if (c == 0) acc += cost;           // grp leaders only
    }
    // fold grp leaders (lanes 0,16,32,48) -> lane 0
    acc += __shfl_xor(acc, 16);
    acc += __shfl_xor(acc, 32);

    if (lane == 0) ls[wid] = acc;
    __syncthreads();
    if (threadIdx.x == 0) {
        float s = 0.f;
        #pragma unroll
        for (int w = 0; w < 8; ++w) s += ls[w];
        blockpart[blockIdx.x] = s;
    }
}

// ---------------- K3: final reduce (1 block, one parallel load round) ------
__global__ __launch_bounds__(256) void k3_final(
        const float* __restrict__ blockpart,
        float* __restrict__ out) {
    const int t = threadIdx.x;             // 0..255
    float s = blockpart[t] + blockpart[t + 256];
    #pragma unroll
    for (int off = 32; off > 0; off >>= 1) s += __shfl_xor(s, off);
    __shared__ float ls[4];
    if ((t & 63) == 0) ls[t >> 6] = s;
    __syncthreads();
    if (t == 0)
        out[0] = (ls[0] + ls[1] + ls[2] + ls[3]) / (float)NPAIRS;
}

extern "C" void kernel_launch(void* const* d_in, const int* in_sizes, int n_in,
                              void* d_out, int out_size, void* d_ws, size_t ws_size,
                              hipStream_t stream) {
    const float4* emb4 = (const float4*)d_in[0];
    const int*    iv   = (const int*)d_in[1];
    const int*    jv   = (const int*)d_in[2];
    float* out = (float*)d_out;

    float* partial   = (float*)d_ws;                 // 128*128
    float* blockpart = partial + K1_BLOCKS * DIM;    // 512

    hipLaunchKernelGGL(k1_colsum, dim3(K1_BLOCKS), dim3(K1_THREADS), 0, stream,
                       emb4, partial);
    hipLaunchKernelGGL(k2_pairs, dim3(K2_BLOCKS), dim3(K2_THREADS), 0, stream,
                       emb4, iv, jv, (const float4*)partial, blockpart);
    hipLaunchKernelGGL(k3_final, dim3(1), dim3(256), 0, stream,
                       blockpart, out);
}